// Round 2
// baseline (310.969 us; speedup 1.0000x reference)
//
#include <hip/hip_runtime.h>
#include <hip/hip_bf16.h>
#include <stdint.h>

// Problem constants
#define B_ROWS 131072
#define DD 256
#define KEXP 8
#define HH 128
#define BM 128        // rows per workgroup
#define NW 8          // waves per workgroup

typedef float  f32x4  __attribute__((ext_vector_type(4)));
typedef short  bf16x8 __attribute__((ext_vector_type(8)));
typedef uint32_t u32x4 __attribute__((ext_vector_type(4)));

__device__ __forceinline__ unsigned short f2bf(float f) {
    uint32_t u = __builtin_bit_cast(uint32_t, f);
    u += 0x7fffu + ((u >> 16) & 1u);   // RTNE
    return (unsigned short)(u >> 16);
}

// exact-erf GELU via Abramowitz-Stegun 7.1.26 (|erf err| <= 1.5e-7)
__device__ __forceinline__ float gelu_erf(float x) {
    float s = x * 0.70710678118654752f;
    float a = fabsf(s);
    float t = __builtin_amdgcn_rcpf(fmaf(0.3275911f, a, 1.0f));
    float p = fmaf(t, 1.061405429f, -1.453152027f);
    p = fmaf(t, p, 1.421413741f);
    p = fmaf(t, p, -0.284496736f);
    p = fmaf(t, p, 0.254829592f);
    float e = __expf(-a * a);
    float Q = p * t * e;                        // = 1 - erf(a)
    float sel = (s >= 0.f) ? (2.0f - Q) : Q;    // 1 + erf(s)
    return 0.5f * x * sel;
}

// Preconvert: W1 -> bf16 [k][h-row][32 slots][8], slot sc holds d-chunk kc = sc ^ (h&7).
//             W2 -> bf16 [k][g-row][16 slots][8], slot sc holds h-chunk kc = sc ^ (g&7).
__global__ void convert_weights(const float* __restrict__ W1, const float* __restrict__ W2,
                                uint16_t* __restrict__ w1o, uint16_t* __restrict__ w2o) {
    int idx = blockIdx.x * blockDim.x + threadIdx.x;
    const int total1 = KEXP * HH * DD;           // 262144
    if (idx < total1) {
        int k   = idx >> 15;
        int rem = idx & 32767;
        int h   = rem >> 8;
        int r2  = rem & 255;
        int sc  = r2 >> 3;                       // 0..31
        int j   = r2 & 7;
        int kc  = sc ^ (h & 7);
        int d   = kc * 8 + j;
        w1o[idx] = f2bf(W1[(k * DD + d) * HH + h]);
        return;
    }
    int idx2 = idx - total1;
    const int total2 = KEXP * HH * HH;           // 131072
    if (idx2 < total2) {
        int k   = idx2 >> 14;
        int rem = idx2 & 16383;
        int gr  = rem >> 7;
        int r2  = rem & 127;
        int sc  = r2 >> 3;                       // 0..15
        int j   = r2 & 7;
        int kc  = sc ^ (gr & 7);
        int h   = kc * 8 + j;
        w2o[idx2] = f2bf(W2[(k * HH + h) * HH + gr]);
    }
}

__global__ __launch_bounds__(512)
void moe_kernel(const float* __restrict__ z, const float* __restrict__ probs,
                const float* __restrict__ b1, const float* __restrict__ b2,
                const float* __restrict__ W3, const float* __restrict__ b3,
                const uint16_t* __restrict__ w1b, const uint16_t* __restrict__ w2b,
                float* __restrict__ out) {
    __shared__ __align__(16) uint16_t w1_lds[HH * DD];    // 64 KB  [h-row][swz d-chunks]
    __shared__ __align__(16) uint16_t w2_lds[HH * HH];    // 32 KB  [g-row][swz h-chunks]
    __shared__ __align__(16) uint16_t h_lds[NW * 2048];   // 32 KB  per-wave [m:16][h:128], XOR-swizzled
    __shared__ __align__(16) float b1_lds[HH];
    __shared__ __align__(16) float b2_lds[HH];
    __shared__ __align__(16) float w3_lds[HH];
    __shared__ __align__(16) float probs_lds[BM * KEXP];  // 4 KB
    __shared__ __align__(16) float preds_lds[BM * KEXP];  // 4 KB

    const int tid  = threadIdx.x;
    const int wave = tid >> 6;
    const int lane = tid & 63;
    const int c    = lane & 15;    // MFMA n-index == our row m; also A m-row for W-fragments
    const int g    = lane >> 4;    // MFMA lane group
    const int wg   = blockIdx.x;
    const long rowbase = (long)wg * BM;

    // stage regime_probs tile (128 x 8 f32)
    {
        float2 v = *(const float2*)(probs + (size_t)wg * (BM * KEXP) + tid * 2);
        *(float2*)(probs_lds + tid * 2) = v;
    }

    // z fragments: lane holds z[row = wave*16 + c][d = kk*32 + 8g + j]  (A/B-compatible layout)
    bf16x8 zf[8];
    {
        const float* zr = z + (rowbase + wave * 16 + c) * DD;
        #pragma unroll
        for (int kk = 0; kk < 8; ++kk) {
            const float* p = zr + kk * 32 + g * 8;
            float4 x0 = *(const float4*)(p);
            float4 x1 = *(const float4*)(p + 4);
            bf16x8 f;
            f[0] = f2bf(x0.x); f[1] = f2bf(x0.y); f[2] = f2bf(x0.z); f[3] = f2bf(x0.w);
            f[4] = f2bf(x1.x); f[5] = f2bf(x1.y); f[6] = f2bf(x1.z); f[7] = f2bf(x1.w);
            zf[kk] = f;
        }
    }

    // wave-private h tile: row m=c is 256 B; swizzle XORs byte bits 4-6 with (c&7)
    char* hbase = (char*)h_lds + wave * 4096 + c * 256;
    const int sw = (c & 7) << 4;

    for (int ke = 0; ke < KEXP; ++ke) {
        __syncthreads();   // previous expert's LDS consumption complete

        // --- stage W1^T[ke] (64KB) and W2^T[ke] (32KB): bf16, pre-swizzled in ws ---
        {
            const u32x4* src1 = (const u32x4*)(w1b + ke * (HH * DD));
            u32x4* dst1 = (u32x4*)w1_lds;
            #pragma unroll
            for (int i = 0; i < 8; ++i) dst1[tid + i * 512] = src1[tid + i * 512];
            const u32x4* src2 = (const u32x4*)(w2b + ke * (HH * HH));
            u32x4* dst2 = (u32x4*)w2_lds;
            #pragma unroll
            for (int i = 0; i < 4; ++i) dst2[tid + i * 512] = src2[tid + i * 512];
            if (tid < HH) {
                b1_lds[tid] = b1[ke * HH + tid];
                b2_lds[tid] = b2[ke * HH + tid];
                w3_lds[tid] = W3[ke * HH + tid];
            }
        }
        __syncthreads();

        // --- Layer 1 (transposed): D1T[h][m] = sum_d W1T[h][d] z[m][d] + b1[h] ---
        // acc[hb][r] = D1T[16hb + 4g + r][m = c]
        f32x4 acc[8];
        #pragma unroll
        for (int hb = 0; hb < 8; ++hb)
            acc[hb] = *(const f32x4*)(b1_lds + 16 * hb + 4 * g);
        #pragma unroll
        for (int kk = 0; kk < 8; ++kk) {
            #pragma unroll
            for (int hb = 0; hb < 8; ++hb) {
                int row  = 16 * hb + c;                    // A m-row = h index
                int slot = (4 * kk + g) ^ (c & 7);         // d-chunk slot (pre-swizzled)
                bf16x8 wf = *(const bf16x8*)(w1_lds + row * 256 + slot * 8);
                acc[hb] = __builtin_amdgcn_mfma_f32_16x16x32_bf16(wf, zf[kk], acc[hb], 0, 0, 0);
            }
        }

        // --- GELU -> bf16 -> h_lds[m=c][h], 8 x ds_write_b64, swizzled ---
        #pragma unroll
        for (int hb = 0; hb < 8; ++hb) {
            unsigned short q0 = f2bf(gelu_erf(acc[hb][0]));
            unsigned short q1 = f2bf(gelu_erf(acc[hb][1]));
            unsigned short q2 = f2bf(gelu_erf(acc[hb][2]));
            unsigned short q3 = f2bf(gelu_erf(acc[hb][3]));
            uint2 w = make_uint2((uint32_t)q0 | ((uint32_t)q1 << 16),
                                 (uint32_t)q2 | ((uint32_t)q3 << 16));
            *(uint2*)(hbase + ((32 * hb + 8 * g) ^ sw)) = w;   // h = 16hb + 4g + {0..3}
        }
        asm volatile("" ::: "memory");   // keep the writes before the reads below

        // --- Layer 2 (transposed): D2T[g2][m] = sum_h W2T[g2][h] h1[m][h] + b2[g2] ---
        f32x4 acc2[8];
        #pragma unroll
        for (int hb2 = 0; hb2 < 8; ++hb2)
            acc2[hb2] = *(const f32x4*)(b2_lds + 16 * hb2 + 4 * g);
        #pragma unroll
        for (int kk = 0; kk < 4; ++kk) {
            // B-fragment: h1[m=c][h = 32kk + 8g + j]  (same-wave LDS, in-order)
            bf16x8 hf = *(const bf16x8*)(hbase + ((64 * kk + 16 * g) ^ sw));
            #pragma unroll
            for (int hb2 = 0; hb2 < 8; ++hb2) {
                int row  = 16 * hb2 + c;                   // A m-row = g2 index
                int slot = (4 * kk + g) ^ (c & 7);
                bf16x8 wf = *(const bf16x8*)(w2_lds + row * 128 + slot * 8);
                acc2[hb2] = __builtin_amdgcn_mfma_f32_16x16x32_bf16(wf, hf, acc2[hb2], 0, 0, 0);
            }
        }

        // --- GELU + layer-3 dot: lane holds g2 = 16hb2 + 4g + r, all for m = c ---
        float part = 0.f;
        #pragma unroll
        for (int hb2 = 0; hb2 < 8; ++hb2) {
            f32x4 w3v = *(const f32x4*)(w3_lds + 16 * hb2 + 4 * g);
            part = fmaf(gelu_erf(acc2[hb2][0]), w3v[0], part);
            part = fmaf(gelu_erf(acc2[hb2][1]), w3v[1], part);
            part = fmaf(gelu_erf(acc2[hb2][2]), w3v[2], part);
            part = fmaf(gelu_erf(acc2[hb2][3]), w3v[3], part);
        }
        // sum across the 4 lane-groups (lanes differing in bits 4,5 share the same m=c)
        part += __shfl_xor(part, 16);
        part += __shfl_xor(part, 32);
        if (g == 0)
            preds_lds[(wave * 16 + c) * KEXP + ke] = part + b3[ke];
    }

    __syncthreads();

    // expert_preds: coalesced 1024 f32 per WG
    {
        float2 v = *(const float2*)(preds_lds + tid * 2);
        *(float2*)(out + B_ROWS + rowbase * KEXP + tid * 2) = v;
    }
    // blended: 128 f32 per WG
    if (tid < BM) {
        const float* pr = probs_lds + tid * KEXP;
        const float* pd = preds_lds + tid * KEXP;
        float s = 0.f;
        #pragma unroll
        for (int k2 = 0; k2 < KEXP; ++k2) s = fmaf(pr[k2], pd[k2], s);
        out[rowbase + tid] = s;
    }
}

extern "C" void kernel_launch(void* const* d_in, const int* in_sizes, int n_in,
                              void* d_out, int out_size, void* d_ws, size_t ws_size,
                              hipStream_t stream) {
    const float* z     = (const float*)d_in[0];
    const float* probs = (const float*)d_in[1];
    const float* W1    = (const float*)d_in[2];
    const float* b1    = (const float*)d_in[3];
    const float* W2    = (const float*)d_in[4];
    const float* b2    = (const float*)d_in[5];
    const float* W3    = (const float*)d_in[6];
    const float* b3    = (const float*)d_in[7];
    float* out = (float*)d_out;

    uint16_t* w1b = (uint16_t*)d_ws;                       // 8*128*256 bf16 = 512 KB
    uint16_t* w2b = w1b + (size_t)KEXP * HH * DD;          // 8*128*128 bf16 = 256 KB

    const int totalw = KEXP * HH * DD + KEXP * HH * HH;    // 393216
    convert_weights<<<(totalw + 255) / 256, 256, 0, stream>>>(W1, W2, w1b, w2b);
    moe_kernel<<<B_ROWS / BM, 512, 0, stream>>>(z, probs, b1, b2, W3, b3, w1b, w2b, out);
}

// Round 4
// 287.390 us; speedup vs baseline: 1.0820x; 1.0820x over previous
//
#include <hip/hip_runtime.h>
#include <hip/hip_bf16.h>
#include <stdint.h>

// Problem constants
#define B_ROWS 131072
#define DD 256
#define KEXP 8
#define HH 128
#define BM 128        // rows per workgroup
#define NW 8          // waves per workgroup

typedef float  f32x4  __attribute__((ext_vector_type(4)));
typedef short  bf16x8 __attribute__((ext_vector_type(8)));

__device__ __forceinline__ unsigned short f2bf(float f) {
    uint32_t u = __builtin_bit_cast(uint32_t, f);
    u += 0x7fffu + ((u >> 16) & 1u);   // RTNE
    return (unsigned short)(u >> 16);
}

// exact-erf GELU via Abramowitz-Stegun 7.1.26 (|erf err| <= 1.5e-7)
__device__ __forceinline__ float gelu_erf(float x) {
    float s = x * 0.70710678118654752f;
    float a = fabsf(s);
    float t = __builtin_amdgcn_rcpf(fmaf(0.3275911f, a, 1.0f));
    float p = fmaf(t, 1.061405429f, -1.453152027f);
    p = fmaf(t, p, 1.421413741f);
    p = fmaf(t, p, -0.284496736f);
    p = fmaf(t, p, 0.254829592f);
    float e = __expf(-a * a);
    float Q = p * t * e;                        // = 1 - erf(a)
    float sel = (s >= 0.f) ? (2.0f - Q) : Q;    // 1 + erf(s)
    return 0.5f * x * sel;
}

// Preconvert: W1 -> bf16 [k][h-row][32 slots][8], slot sc holds d-chunk kc = sc ^ (h&7).
//             W2 -> bf16 [k][g-row][16 slots][8], slot sc holds h-chunk kc = sc ^ (gr&7),
//                   with the h (k) axis permuted by pi: h_bit4 <- k_bit2, h_bit3 <- k_bit4,
//                   h_bit2 <- k_bit3 (3-cycle on bits {2,3,4}; other bits identity), so the
//                   layer-1 C/D fragments (gelu'd, packed pairwise) feed layer-2's B operand
//                   directly with no LDS round-trip.
//                   Derivation: pa_{kk2}[j] holds h[32*kk2 + 16*(j>=4) + 4g + (j&3)] while
//                   the MFMA k-position is 32*kk2 + 8g + j.
__global__ void convert_weights(const float* __restrict__ W1, const float* __restrict__ W2,
                                uint16_t* __restrict__ w1o, uint16_t* __restrict__ w2o) {
    int idx = blockIdx.x * blockDim.x + threadIdx.x;
    const int total1 = KEXP * HH * DD;           // 262144
    if (idx < total1) {
        int k   = idx >> 15;
        int rem = idx & 32767;
        int h   = rem >> 8;
        int r2  = rem & 255;
        int sc  = r2 >> 3;                       // 0..31
        int j   = r2 & 7;
        int kc  = sc ^ (h & 7);
        int d   = kc * 8 + j;
        w1o[idx] = f2bf(W1[(k * DD + d) * HH + h]);
        return;
    }
    int idx2 = idx - total1;
    const int total2 = KEXP * HH * HH;           // 131072
    if (idx2 < total2) {
        int k   = idx2 >> 14;
        int rem = idx2 & 16383;
        int gr  = rem >> 7;
        int r2  = rem & 127;
        int sc  = r2 >> 3;                       // 0..15
        int j   = r2 & 7;
        int kk  = (sc ^ (gr & 7)) * 8 + j;       // logical k position
        int h   = (kk & ~0x1C) | ((kk & 4) << 2) | ((kk & 0x18) >> 1);  // pi (3-cycle 2->4->3->2)
        w2o[idx2] = f2bf(W2[(k * HH + h) * HH + gr]);
    }
}

// stage 32KB: 8 waves x 4 x (64 lanes x 16B). LDS dest is wave-uniform base + lane*16 (HW).
__device__ __forceinline__ void stage32k(const uint16_t* __restrict__ src, uint16_t* dst,
                                         int wave, int lane) {
    const char* s = (const char*)src + wave * 1024 + lane * 16;
    char* d = (char*)dst + wave * 1024;
    #pragma unroll
    for (int i = 0; i < 4; ++i)
        __builtin_amdgcn_global_load_lds(
            (const __attribute__((address_space(1))) void*)(s + i * 8192),
            (__attribute__((address_space(3))) void*)(d + i * 8192), 16, 0, 0);
}

__device__ __forceinline__ bf16x8 gelu_pack(f32x4 lo, f32x4 hi) {
    bf16x8 r;
    r[0] = f2bf(gelu_erf(lo[0])); r[1] = f2bf(gelu_erf(lo[1]));
    r[2] = f2bf(gelu_erf(lo[2])); r[3] = f2bf(gelu_erf(lo[3]));
    r[4] = f2bf(gelu_erf(hi[0])); r[5] = f2bf(gelu_erf(hi[1]));
    r[6] = f2bf(gelu_erf(hi[2])); r[7] = f2bf(gelu_erf(hi[3]));
    return r;
}

__global__ __launch_bounds__(512, 4)
void moe_kernel(const float* __restrict__ z, const float* __restrict__ probs,
                const float* __restrict__ b1, const float* __restrict__ b2,
                const float* __restrict__ W3, const float* __restrict__ b3,
                const uint16_t* __restrict__ w1b, const uint16_t* __restrict__ w2b,
                float* __restrict__ out) {
    __shared__ __align__(16) uint16_t wbuf[2][16384];     // 2 x 32 KB ping-pong
    __shared__ __align__(16) float preds_lds[BM * KEXP];  // 4 KB

    const int tid  = threadIdx.x;
    const int wave = tid >> 6;
    const int lane = tid & 63;
    const int c    = lane & 15;
    const int g    = lane >> 4;
    const int wg   = blockIdx.x;
    const long rowbase = (long)wg * BM;

    // z fragments: lane holds z[row = wave*16 + c][d = kk*32 + 8g + j]
    bf16x8 zf[8];
    {
        const float* zr = z + (rowbase + wave * 16 + c) * DD;
        #pragma unroll
        for (int kk = 0; kk < 8; ++kk) {
            const float* p = zr + kk * 32 + g * 8;
            float4 x0 = *(const float4*)(p);
            float4 x1 = *(const float4*)(p + 4);
            bf16x8 f;
            f[0] = f2bf(x0.x); f[1] = f2bf(x0.y); f[2] = f2bf(x0.z); f[3] = f2bf(x0.w);
            f[4] = f2bf(x1.x); f[5] = f2bf(x1.y); f[6] = f2bf(x1.z); f[7] = f2bf(x1.w);
            zf[kk] = f;
        }
    }

    // prologue: stage expert 0, W1 half 0
    stage32k(w1b, wbuf[0], wave, lane);
    __syncthreads();

    int cur = 0;
    const int cswz = c & 7;

    for (int ke = 0; ke < KEXP; ++ke) {
        bf16x8 pa0, pa1, pa2, pa3;

        // ---- phase r0: W1 rows 0-63 (in wbuf[cur]); stage W1 rows 64-127 ----
        {
            stage32k(w1b + ke * 32768 + 16384, wbuf[cur ^ 1], wave, lane);
            const float* bb = b1 + ke * HH;
            f32x4 a0 = *(const f32x4*)(bb +  0 + 4 * g);
            f32x4 a1 = *(const f32x4*)(bb + 16 + 4 * g);
            f32x4 a2 = *(const f32x4*)(bb + 32 + 4 * g);
            f32x4 a3 = *(const f32x4*)(bb + 48 + 4 * g);
            const uint16_t* wb = wbuf[cur];
            #pragma unroll
            for (int kk = 0; kk < 8; ++kk) {
                int slot = (4 * kk + g) ^ cswz;
                const uint16_t* base = wb + c * 256 + slot * 8;
                a0 = __builtin_amdgcn_mfma_f32_16x16x32_bf16(*(const bf16x8*)(base        ), zf[kk], a0, 0, 0, 0);
                a1 = __builtin_amdgcn_mfma_f32_16x16x32_bf16(*(const bf16x8*)(base +  4096), zf[kk], a1, 0, 0, 0);
                a2 = __builtin_amdgcn_mfma_f32_16x16x32_bf16(*(const bf16x8*)(base +  8192), zf[kk], a2, 0, 0, 0);
                a3 = __builtin_amdgcn_mfma_f32_16x16x32_bf16(*(const bf16x8*)(base + 12288), zf[kk], a3, 0, 0, 0);
            }
            pa0 = gelu_pack(a0, a1);   // h rows 0-31 block (pi-packed)
            pa1 = gelu_pack(a2, a3);   // h rows 32-63 block
            __syncthreads(); cur ^= 1;
        }

        // ---- phase r1: W1 rows 64-127; stage W2 ----
        {
            stage32k(w2b + ke * 16384, wbuf[cur ^ 1], wave, lane);
            const float* bb = b1 + ke * HH + 64;
            f32x4 a0 = *(const f32x4*)(bb +  0 + 4 * g);
            f32x4 a1 = *(const f32x4*)(bb + 16 + 4 * g);
            f32x4 a2 = *(const f32x4*)(bb + 32 + 4 * g);
            f32x4 a3 = *(const f32x4*)(bb + 48 + 4 * g);
            const uint16_t* wb = wbuf[cur];
            #pragma unroll
            for (int kk = 0; kk < 8; ++kk) {
                int slot = (4 * kk + g) ^ cswz;
                const uint16_t* base = wb + c * 256 + slot * 8;
                a0 = __builtin_amdgcn_mfma_f32_16x16x32_bf16(*(const bf16x8*)(base        ), zf[kk], a0, 0, 0, 0);
                a1 = __builtin_amdgcn_mfma_f32_16x16x32_bf16(*(const bf16x8*)(base +  4096), zf[kk], a1, 0, 0, 0);
                a2 = __builtin_amdgcn_mfma_f32_16x16x32_bf16(*(const bf16x8*)(base +  8192), zf[kk], a2, 0, 0, 0);
                a3 = __builtin_amdgcn_mfma_f32_16x16x32_bf16(*(const bf16x8*)(base + 12288), zf[kk], a3, 0, 0, 0);
            }
            pa2 = gelu_pack(a0, a1);   // h rows 64-95
            pa3 = gelu_pack(a2, a3);   // h rows 96-127
            __syncthreads(); cur ^= 1;
        }

        // ---- phase r2: layer 2 from wbuf[cur]; stage next expert's W1 half 0 ----
        {
            if (ke + 1 < KEXP) stage32k(w1b + (ke + 1) * 32768, wbuf[cur ^ 1], wave, lane);
            const float* bb = b2 + ke * HH;
            f32x4 q0 = *(const f32x4*)(bb +   0 + 4 * g);
            f32x4 q1 = *(const f32x4*)(bb +  16 + 4 * g);
            f32x4 q2 = *(const f32x4*)(bb +  32 + 4 * g);
            f32x4 q3 = *(const f32x4*)(bb +  48 + 4 * g);
            f32x4 q4 = *(const f32x4*)(bb +  64 + 4 * g);
            f32x4 q5 = *(const f32x4*)(bb +  80 + 4 * g);
            f32x4 q6 = *(const f32x4*)(bb +  96 + 4 * g);
            f32x4 q7 = *(const f32x4*)(bb + 112 + 4 * g);
            const uint16_t* wb = wbuf[cur];
            #pragma unroll
            for (int kk2 = 0; kk2 < 4; ++kk2) {
                bf16x8 pa = (kk2 == 0) ? pa0 : (kk2 == 1) ? pa1 : (kk2 == 2) ? pa2 : pa3;
                int slot = (4 * kk2 + g) ^ cswz;
                const uint16_t* base = wb + c * 128 + slot * 8;
                q0 = __builtin_amdgcn_mfma_f32_16x16x32_bf16(*(const bf16x8*)(base        ), pa, q0, 0, 0, 0);
                q1 = __builtin_amdgcn_mfma_f32_16x16x32_bf16(*(const bf16x8*)(base +  2048), pa, q1, 0, 0, 0);
                q2 = __builtin_amdgcn_mfma_f32_16x16x32_bf16(*(const bf16x8*)(base +  4096), pa, q2, 0, 0, 0);
                q3 = __builtin_amdgcn_mfma_f32_16x16x32_bf16(*(const bf16x8*)(base +  6144), pa, q3, 0, 0, 0);
                q4 = __builtin_amdgcn_mfma_f32_16x16x32_bf16(*(const bf16x8*)(base +  8192), pa, q4, 0, 0, 0);
                q5 = __builtin_amdgcn_mfma_f32_16x16x32_bf16(*(const bf16x8*)(base + 10240), pa, q5, 0, 0, 0);
                q6 = __builtin_amdgcn_mfma_f32_16x16x32_bf16(*(const bf16x8*)(base + 12288), pa, q6, 0, 0, 0);
                q7 = __builtin_amdgcn_mfma_f32_16x16x32_bf16(*(const bf16x8*)(base + 14336), pa, q7, 0, 0, 0);
            }

            // GELU + layer-3 dot: lane holds g2 = 16*hb2 + 4g + r, m = c
            const float* w3p = W3 + ke * HH;
            float part = 0.f;
            f32x4 w3v;
            #define DOT(qq, off) \
                w3v = *(const f32x4*)(w3p + off + 4 * g); \
                part = fmaf(gelu_erf(qq[0]), w3v[0], part); \
                part = fmaf(gelu_erf(qq[1]), w3v[1], part); \
                part = fmaf(gelu_erf(qq[2]), w3v[2], part); \
                part = fmaf(gelu_erf(qq[3]), w3v[3], part);
            DOT(q0,   0) DOT(q1,  16) DOT(q2,  32) DOT(q3,  48)
            DOT(q4,  64) DOT(q5,  80) DOT(q6,  96) DOT(q7, 112)
            #undef DOT
            part += __shfl_xor(part, 16);
            part += __shfl_xor(part, 32);
            if (g == 0)
                preds_lds[(wave * 16 + c) * KEXP + ke] = part + b3[ke];
            __syncthreads(); cur ^= 1;
        }
    }

    // expert_preds: coalesced 1024 f32 per WG
    {
        float2 v = *(const float2*)(preds_lds + tid * 2);
        *(float2*)(out + B_ROWS + rowbase * KEXP + tid * 2) = v;
    }
    // blended: 128 f32 per WG (probs straight from global, coalesced)
    if (tid < BM) {
        const float* pr = probs + (rowbase + tid) * KEXP;
        float4 p0 = *(const float4*)(pr);
        float4 p1 = *(const float4*)(pr + 4);
        const float* pd = preds_lds + tid * KEXP;
        float s = 0.f;
        s = fmaf(p0.x, pd[0], s); s = fmaf(p0.y, pd[1], s);
        s = fmaf(p0.z, pd[2], s); s = fmaf(p0.w, pd[3], s);
        s = fmaf(p1.x, pd[4], s); s = fmaf(p1.y, pd[5], s);
        s = fmaf(p1.z, pd[6], s); s = fmaf(p1.w, pd[7], s);
        out[rowbase + tid] = s;
    }
}

extern "C" void kernel_launch(void* const* d_in, const int* in_sizes, int n_in,
                              void* d_out, int out_size, void* d_ws, size_t ws_size,
                              hipStream_t stream) {
    const float* z     = (const float*)d_in[0];
    const float* probs = (const float*)d_in[1];
    const float* W1    = (const float*)d_in[2];
    const float* b1    = (const float*)d_in[3];
    const float* W2    = (const float*)d_in[4];
    const float* b2    = (const float*)d_in[5];
    const float* W3    = (const float*)d_in[6];
    const float* b3    = (const float*)d_in[7];
    float* out = (float*)d_out;

    uint16_t* w1b = (uint16_t*)d_ws;                       // 8*128*256 bf16 = 512 KB
    uint16_t* w2b = w1b + (size_t)KEXP * HH * DD;          // 8*128*128 bf16 = 256 KB

    const int totalw = KEXP * HH * DD + KEXP * HH * HH;    // 393216
    convert_weights<<<(totalw + 255) / 256, 256, 0, stream>>>(W1, W2, w1b, w2b);
    moe_kernel<<<B_ROWS / BM, 512, 0, stream>>>(z, probs, b1, b2, W3, b3, w1b, w2b, out);
}